// Round 6
// baseline (238.972 us; speedup 1.0000x reference)
//
#include <hip/hip_runtime.h>
#include <stdint.h>

#define NB    1024   // batch
#define NUM   512    // nodes
#define HD    64     // hidden dim
#define NE    4096   // edges
#define MAIN  10     // softmax segment
#define HBS   72     // HB row stride (shorts): 144 B -> 16B-aligned b128, bank-rotating

typedef __attribute__((ext_vector_type(8))) short short8;
typedef __attribute__((ext_vector_type(4))) float f32x4;

__device__ __forceinline__ short f2bf(float f) {
    uint32_t u = __float_as_uint(f);
    u += 0x7fffu + ((u >> 16) & 1u);   // RNE
    return (short)(u >> 16);
}
__device__ __forceinline__ float bf2f(short s) {
    return __uint_as_float(((uint32_t)(uint16_t)s) << 16);
}

// ---------------------------------------------------------------------------
// Prep 1: degree -> dinv -> col-sorted CSR with packed edges (row<<16 | bf16 norm).
// Single block, 512 threads.
// ---------------------------------------------------------------------------
__global__ __launch_bounds__(512) void prep_csr(const int* __restrict__ erow,
                                                const int* __restrict__ ecol,
                                                int* __restrict__ ptr,
                                                int* __restrict__ epk) {
    __shared__ int   sdeg[NUM];
    __shared__ int   sscan[NUM];
    __shared__ float sdinv[NUM];
    __shared__ int   curs[NUM];
    const int t = threadIdx.x;

    sdeg[t] = 0;
    __syncthreads();
    for (int e = t; e < NE; e += 512) atomicAdd(&sdeg[ecol[e]], 1);
    __syncthreads();
    {
        int d = sdeg[t];
        sdinv[t] = d > 0 ? rsqrtf((float)d) : 0.0f;
        sscan[t] = d;
    }
    __syncthreads();
    for (int ofs = 1; ofs < NUM; ofs <<= 1) {
        int v = (t >= ofs) ? sscan[t - ofs] : 0;
        __syncthreads();
        sscan[t] += v;
        __syncthreads();
    }
    {
        int excl = (t == 0) ? 0 : sscan[t - 1];
        curs[t] = excl;
        ptr[t]  = excl;
        if (t == NUM - 1) ptr[NUM] = sscan[NUM - 1];
    }
    __syncthreads();
    for (int e = t; e < NE; e += 512) {
        int c = ecol[e], r = erow[e];
        int p = atomicAdd(&curs[c], 1);
        unsigned nb = (unsigned short)f2bf(sdinv[r] * sdinv[c]);
        epk[p] = (r << 16) | (int)nb;
    }
}

// ---------------------------------------------------------------------------
// Prep 2: E1[node][dim] = emb @ W1 (bf16);  W2T[dout][din] = W2^T (bf16).
// ---------------------------------------------------------------------------
__global__ __launch_bounds__(256) void prep_cast(const float* __restrict__ emb,
                                                 const float* __restrict__ W1,
                                                 const float* __restrict__ W2,
                                                 short* __restrict__ E1,
                                                 short* __restrict__ W2T) {
    int g = blockIdx.x * 256 + threadIdx.x;
    if (g < NUM * HD) {
        int node = g >> 6, dim = g & 63;
        float acc = 0.0f;
        #pragma unroll
        for (int k = 0; k < HD; ++k) acc += emb[node * HD + k] * W1[k * HD + dim];
        E1[g] = f2bf(acc);
    } else if (g < NUM * HD + HD * HD) {
        int j = g - NUM * HD;
        int dout = j >> 6, din = j & 63;
        W2T[j] = f2bf(W2[din * HD + dout]);
    }
}

// ---------------------------------------------------------------------------
// Fused per-batch kernel: 1024 threads (16 waves) per batch element.
// All activations + edge list in LDS; aggregation is sparse gather (SpMM),
// only the h1@W2 layer uses MFMA.
// ---------------------------------------------------------------------------
__global__ __launch_bounds__(1024, 4) void gcn_all(
    const float* __restrict__ x, const short* __restrict__ E1,
    const short* __restrict__ W2T,
    const float* __restrict__ b1, const float* __restrict__ b2,
    const float* __restrict__ W3, const float* __restrict__ b3,
    const int* __restrict__ sptrg, const int* __restrict__ epkg,
    float* __restrict__ out)
{
    __shared__ short HA[NUM * HD];     // 65536 B  [node][64] (B1, later g = h1@W2)
    __shared__ short HB[NUM * HBS];    // 73728 B  [node][72] (h1; MFMA A-operand)
    __shared__ int   eps[NE];          // 16384 B  packed edges (row<<16 | bf16 norm)
    __shared__ int   sptr[514];        //  2056 B
    __shared__ float tv[NUM];          //  2048 B  per-node h2.W3
    __shared__ float slog[NUM];        //  2048 B  logits
    __shared__ float sred[2];

    const int t    = threadIdx.x;
    const int b    = blockIdx.x;
    const int lane = t & 63;
    const int wave = t >> 6;           // 0..15
    const int q    = lane >> 4;
    const int l15  = lane & 15;
    const int s    = lane & 31;        // col-pair index within half-wave
    const int h    = lane >> 5;        // which target of the c-pair

    // ---- stage: edges, csr ptr
    *(int4*)&eps[t * 4] = *(const int4*)&epkg[t * 4];
    if (t < 514) sptr[t] = sptrg[t < 513 ? t : 512];

    // ---- build HA = B1:  B1[r][d] = x[b,r] * E1[r][d]
    #pragma unroll
    for (int p = 0; p < 4; ++p) {
        int i = t + p * 1024;          // 4096 groups of 8 dims
        int r = i >> 3, d8 = (i & 7) * 8;
        float xr = x[b * NUM + r];
        short8 e = *(const short8*)&E1[r * HD + d8];
        short8 o;
        #pragma unroll
        for (int j = 0; j < 8; ++j) o[j] = f2bf(xr * bf2f(e[j]));
        *(short8*)&HA[r * HD + d8] = o;
    }
    __syncthreads();

    // per-lane constants (cols 2s, 2s+1)
    const float2 b1p = *(const float2*)&b1[s * 2];
    const float2 b2p = *(const float2*)&b2[s * 2];
    const float2 w3p = *(const float2*)&W3[s * 2];

    // ---- SpMM1: h1 = relu(S @ B1 + b1) -> HB (padded stride)
    #pragma unroll 1
    for (int cp = 0; cp < 16; ++cp) {
        int c = wave * 32 + cp * 2 + h;
        int e0 = sptr[c], e1 = sptr[c + 1];
        float ax0 = 0.f, ay0 = 0.f, ax1 = 0.f, ay1 = 0.f;
        int e = e0;
        for (; e + 2 <= e1; e += 2) {
            unsigned p0 = (unsigned)eps[e], p1 = (unsigned)eps[e + 1];
            float n0 = __uint_as_float(p0 << 16);
            float n1 = __uint_as_float(p1 << 16);
            unsigned d0 = *(const unsigned*)&HA[(p0 >> 16) * HD + s * 2];
            unsigned d1 = *(const unsigned*)&HA[(p1 >> 16) * HD + s * 2];
            ax0 = fmaf(n0, __uint_as_float(d0 << 16), ax0);
            ay0 = fmaf(n0, __uint_as_float(d0 & 0xffff0000u), ay0);
            ax1 = fmaf(n1, __uint_as_float(d1 << 16), ax1);
            ay1 = fmaf(n1, __uint_as_float(d1 & 0xffff0000u), ay1);
        }
        if (e < e1) {
            unsigned p0 = (unsigned)eps[e];
            float n0 = __uint_as_float(p0 << 16);
            unsigned d0 = *(const unsigned*)&HA[(p0 >> 16) * HD + s * 2];
            ax0 = fmaf(n0, __uint_as_float(d0 << 16), ax0);
            ay0 = fmaf(n0, __uint_as_float(d0 & 0xffff0000u), ay0);
        }
        float ax = fmaxf(ax0 + ax1 + b1p.x, 0.0f);
        float ay = fmaxf(ay0 + ay1 + b1p.y, 0.0f);
        unsigned pk = ((unsigned)(unsigned short)f2bf(ay) << 16)
                    | (unsigned)(unsigned short)f2bf(ax);
        *(unsigned*)&HB[c * HBS + s * 2] = pk;
    }
    __syncthreads();

    // ---- MFMA: g = h1 @ W2 -> HA[node][dout]  (wave = 32-node strip)
    {
        short8 bfr[2][4];
        #pragma unroll
        for (int ks = 0; ks < 2; ++ks)
            #pragma unroll
            for (int nt = 0; nt < 4; ++nt)
                bfr[ks][nt] = *(const short8*)&W2T[(nt * 16 + l15) * HD + ks * 32 + q * 8];
        f32x4 acc[2][4];
        #pragma unroll
        for (int mt = 0; mt < 2; ++mt)
            #pragma unroll
            for (int nt = 0; nt < 4; ++nt) acc[mt][nt] = (f32x4){0.f, 0.f, 0.f, 0.f};
        const int mbase = wave * 32;
        #pragma unroll
        for (int mt = 0; mt < 2; ++mt)
            #pragma unroll
            for (int ks = 0; ks < 2; ++ks) {
                short8 af = *(const short8*)&HB[(mbase + mt * 16 + l15) * HBS
                                                + ks * 32 + q * 8];
                #pragma unroll
                for (int nt = 0; nt < 4; ++nt)
                    acc[mt][nt] = __builtin_amdgcn_mfma_f32_16x16x32_bf16(
                        af, bfr[ks][nt], acc[mt][nt], 0, 0, 0);
            }
        // C/D: col = l15 (dout), row = q*4 + i (node within 16-tile)
        #pragma unroll
        for (int mt = 0; mt < 2; ++mt)
            #pragma unroll
            for (int nt = 0; nt < 4; ++nt)
                #pragma unroll
                for (int i = 0; i < 4; ++i)
                    HA[(mbase + mt * 16 + q * 4 + i) * HD + nt * 16 + l15] =
                        f2bf(acc[mt][nt][i]);
    }
    __syncthreads();

    // ---- SpMM2 + fused epilogue: tv[c] = sum_d relu((S@g)[c,d] + b2[d]) * W3[d]
    #pragma unroll 1
    for (int cp = 0; cp < 16; ++cp) {
        int c = wave * 32 + cp * 2 + h;
        int e0 = sptr[c], e1 = sptr[c + 1];
        float ax0 = 0.f, ay0 = 0.f, ax1 = 0.f, ay1 = 0.f;
        int e = e0;
        for (; e + 2 <= e1; e += 2) {
            unsigned p0 = (unsigned)eps[e], p1 = (unsigned)eps[e + 1];
            float n0 = __uint_as_float(p0 << 16);
            float n1 = __uint_as_float(p1 << 16);
            unsigned d0 = *(const unsigned*)&HA[(p0 >> 16) * HD + s * 2];
            unsigned d1 = *(const unsigned*)&HA[(p1 >> 16) * HD + s * 2];
            ax0 = fmaf(n0, __uint_as_float(d0 << 16), ax0);
            ay0 = fmaf(n0, __uint_as_float(d0 & 0xffff0000u), ay0);
            ax1 = fmaf(n1, __uint_as_float(d1 << 16), ax1);
            ay1 = fmaf(n1, __uint_as_float(d1 & 0xffff0000u), ay1);
        }
        if (e < e1) {
            unsigned p0 = (unsigned)eps[e];
            float n0 = __uint_as_float(p0 << 16);
            unsigned d0 = *(const unsigned*)&HA[(p0 >> 16) * HD + s * 2];
            ax0 = fmaf(n0, __uint_as_float(d0 << 16), ax0);
            ay0 = fmaf(n0, __uint_as_float(d0 & 0xffff0000u), ay0);
        }
        float v = fmaxf(ax0 + ax1 + b2p.x, 0.0f) * w3p.x
                + fmaxf(ay0 + ay1 + b2p.y, 0.0f) * w3p.y;
        // reduce over the 32 lanes of this half-wave
        v += __shfl_xor(v, 1, 64);
        v += __shfl_xor(v, 2, 64);
        v += __shfl_xor(v, 4, 64);
        v += __shfl_xor(v, 8, 64);
        v += __shfl_xor(v, 16, 64);
        if (s == 0) tv[c] = v;
    }
    __syncthreads();

    // ---- SpMM3: slog[c] = (S @ tv)[c] + b3
    if (t < NUM) {
        int e0 = sptr[t], e1 = sptr[t + 1];
        float a = 0.0f;
        for (int e = e0; e < e1; ++e) {
            unsigned pe = (unsigned)eps[e];
            a = fmaf(__uint_as_float(pe << 16), tv[pe >> 16], a);
        }
        slog[t] = a + b3[0];
    }
    __syncthreads();

    // ---- softmax stats over [0, MAIN) on one wave
    if (t < 64) {
        float v = (t < MAIN) ? slog[t] : -1e30f;
        float m = v;
        m = fmaxf(m, __shfl_xor(m, 1, 64));
        m = fmaxf(m, __shfl_xor(m, 2, 64));
        m = fmaxf(m, __shfl_xor(m, 4, 64));
        m = fmaxf(m, __shfl_xor(m, 8, 64));   // lanes 0..15 all hold max
        float ev = (t < MAIN) ? __expf(v - m) : 0.0f;
        ev += __shfl_xor(ev, 1, 64);
        ev += __shfl_xor(ev, 2, 64);
        ev += __shfl_xor(ev, 4, 64);
        ev += __shfl_xor(ev, 8, 64);
        if (t == 0) { sred[0] = m; sred[1] = ev; }
    }
    __syncthreads();

    if (t < NUM) {
        float l = slog[t];
        float o = (t < MAIN) ? __expf(l - sred[0]) / sred[1]
                             : 1.0f / (1.0f + __expf(-l));
        out[b * NUM + t] = o;
    }
}

// ---------------------------------------------------------------------------
extern "C" void kernel_launch(void* const* d_in, const int* in_sizes, int n_in,
                              void* d_out, int out_size, void* d_ws, size_t ws_size,
                              hipStream_t stream) {
    const float* x    = (const float*)d_in[0];
    const float* emb  = (const float*)d_in[1];
    const float* W1   = (const float*)d_in[2];
    const float* b1   = (const float*)d_in[3];
    const float* W2   = (const float*)d_in[4];
    const float* b2   = (const float*)d_in[5];
    const float* W3   = (const float*)d_in[6];
    const float* b3   = (const float*)d_in[7];
    const int*   erow = (const int*)d_in[8];
    const int*   ecol = (const int*)d_in[9];

    char* ws = (char*)d_ws;
    int*   sptr = (int*)ws;                 // 513 ints   [0, 2052)
    int*   epk  = (int*)(ws + 2176);        // 4096 ints  [2176, 18560)
    short* E1   = (short*)(ws + 18560);     // 32768 sh   [18560, 84096)
    short* W2T  = (short*)(ws + 84096);     // 4096 sh    [84096, 92288)

    prep_csr<<<1, 512, 0, stream>>>(erow, ecol, sptr, epk);
    prep_cast<<<144, 256, 0, stream>>>(emb, W1, W2, E1, W2T);
    gcn_all<<<NB, 1024, 0, stream>>>(x, E1, W2T, b1, b2, W3, b3, sptr, epk,
                                     (float*)d_out);
}

// Round 7
// 161.472 us; speedup vs baseline: 1.4800x; 1.4800x over previous
//
#include <hip/hip_runtime.h>
#include <stdint.h>

#define NB    1024   // batch
#define NUM   512    // nodes
#define HD    64     // hidden dim
#define NE    4096   // edges
#define MAIN  10     // softmax segment
#define HBS   72     // HB row stride (shorts): 144 B, 16B-aligned b128 slots

typedef __attribute__((ext_vector_type(8))) short short8;
typedef __attribute__((ext_vector_type(4))) float f32x4;

__device__ __forceinline__ short f2bf(float f) {
    uint32_t u = __float_as_uint(f);
    u += 0x7fffu + ((u >> 16) & 1u);   // RNE
    return (short)(u >> 16);
}
__device__ __forceinline__ float bf2f(short s) {
    return __uint_as_float(((uint32_t)(uint16_t)s) << 16);
}

// ---------------------------------------------------------------------------
// Single prep launch. Block 0: degree -> dinv -> degree-sorted ranks (counting
// sort) -> rank-CSR + packed edges (row<<16 | bf16 norm). Blocks 1..72: cast
// E1 = emb@W1 (bf16) and W2T = W2^T (bf16).
// ---------------------------------------------------------------------------
__global__ __launch_bounds__(512) void prep_all(
    const int* __restrict__ erow, const int* __restrict__ ecol,
    const float* __restrict__ emb, const float* __restrict__ W1,
    const float* __restrict__ W2,
    int* __restrict__ rsptr, int* __restrict__ colmap, int* __restrict__ epk,
    short* __restrict__ E1, short* __restrict__ W2T)
{
    const int t = threadIdx.x;
    if (blockIdx.x != 0) {
        int g = (blockIdx.x - 1) * 512 + t;     // 72 blocks x 512 = 36864
        if (g < NUM * HD) {
            int node = g >> 6, dim = g & 63;
            float acc = 0.0f;
            #pragma unroll
            for (int k = 0; k < HD; ++k) acc += emb[node * HD + k] * W1[k * HD + dim];
            E1[g] = f2bf(acc);
        } else if (g < NUM * HD + HD * HD) {
            int j = g - NUM * HD;
            int dout = j >> 6, din = j & 63;
            W2T[j] = f2bf(W2[din * HD + dout]);
        }
        return;
    }

    __shared__ int   sdeg[NUM];
    __shared__ int   aux[NUM];      // histogram / scan buffer
    __shared__ float sdinv[NUM];
    __shared__ int   rankof[NUM];
    __shared__ int   curs[NUM];
    __shared__ int   rdeg[NUM];

    sdeg[t] = 0;
    __syncthreads();
    for (int e = t; e < NE; e += 512) atomicAdd(&sdeg[ecol[e]], 1);
    __syncthreads();
    const int deg = sdeg[t];
    const int dbin = deg < NUM ? deg : NUM - 1;
    sdinv[t] = deg > 0 ? rsqrtf((float)deg) : 0.0f;
    aux[t] = 0;
    __syncthreads();
    atomicAdd(&aux[dbin], 1);
    __syncthreads();
    // inclusive scan of histogram
    for (int ofs = 1; ofs < NUM; ofs <<= 1) {
        int v = (t >= ofs) ? aux[t - ofs] : 0;
        __syncthreads();
        aux[t] += v;
        __syncthreads();
    }
    curs[t] = (t == 0) ? 0 : aux[t - 1];       // bin cursors (exclusive)
    __syncthreads();
    const int r = atomicAdd(&curs[dbin], 1);   // rank (degree-sorted)
    rankof[t] = r;
    rdeg[r]   = deg;
    colmap[r] = t;
    __syncthreads();
    // inclusive scan of rank-ordered degrees -> rank CSR
    for (int ofs = 1; ofs < NUM; ofs <<= 1) {
        int v = (t >= ofs) ? rdeg[t - ofs] : 0;
        __syncthreads();
        rdeg[t] += v;
        __syncthreads();
    }
    rsptr[t] = (t == 0) ? 0 : rdeg[t - 1];
    if (t == NUM - 1) rsptr[NUM] = rdeg[NUM - 1];
    __syncthreads();
    const int myrank = rankof[t];
    curs[t] = (myrank == 0) ? 0 : rdeg[myrank - 1];   // per-ORIGINAL-col cursor
    __syncthreads();
    for (int e = t; e < NE; e += 512) {
        int c = ecol[e], rr = erow[e];
        int p = atomicAdd(&curs[c], 1);
        unsigned nb = (unsigned short)f2bf(sdinv[rr] * sdinv[c]);
        epk[p] = (rr << 16) | (int)nb;
    }
}

// ---------------------------------------------------------------------------
// Fused per-batch kernel: 1024 threads (16 waves). Sparse aggregation with
// 8 dims/lane (ds_read_b128), 8 lanes per column, 8 columns per wave,
// degree-sorted ranks for divergence-free groups + balanced waves.
// ---------------------------------------------------------------------------
__global__ __launch_bounds__(1024, 4) void gcn_all(
    const float* __restrict__ x, const short* __restrict__ E1,
    const short* __restrict__ W2T,
    const float* __restrict__ b1, const float* __restrict__ b2,
    const float* __restrict__ W3, const float* __restrict__ b3,
    const int* __restrict__ rsptrg, const int* __restrict__ colmapg,
    const int* __restrict__ epkg,
    float* __restrict__ out)
{
    __shared__ short HA[NUM * HD];     // 65536 B  [node][64] (B1, later g = h1@W2)
    __shared__ short HB[NUM * HBS];    // 73728 B  [node][72] (h1); reused: tv, slog
    __shared__ int   eps[NE];          // 16384 B
    __shared__ int   sptr[513];
    __shared__ int   scm[NUM];         //  2048 B  rank -> original column
    __shared__ float sred[2];

    float* tv   = (float*)HB;          // [0,512) floats   (alive after MFMA phase)
    float* slog = ((float*)HB) + NUM;  // [512,1024) floats

    const int t    = threadIdx.x;
    const int b    = blockIdx.x;
    const int lane = t & 63;
    const int wave = t >> 6;           // 0..15
    const int q    = lane >> 4;
    const int l15  = lane & 15;
    const int grp  = lane >> 3;        // 0..7: column slot within wave
    const int dbase = (lane & 7) * 8;  // this lane's 8-dim strip

    // ---- stage: edges, rank-CSR, colmap
    *(int4*)&eps[t * 4] = *(const int4*)&epkg[t * 4];
    if (t < 513) sptr[t] = rsptrg[t];
    if (t < NUM) scm[t] = colmapg[t];

    // ---- build HA = B1: B1[r][d] = x[b,r] * E1[r][d]
    #pragma unroll
    for (int p = 0; p < 4; ++p) {
        int i = t + p * 1024;
        int r = i >> 3, d8 = (i & 7) * 8;
        float xr = x[b * NUM + r];
        short8 e = *(const short8*)&E1[r * HD + d8];
        short8 o;
        #pragma unroll
        for (int j = 0; j < 8; ++j) o[j] = f2bf(xr * bf2f(e[j]));
        *(short8*)&HA[r * HD + d8] = o;
    }

    // per-lane bias/weight strips for its 8 dims
    float b1v[8], b2v[8], w3v[8];
    {
        f32x4 u0 = *(const f32x4*)&b1[dbase], u1 = *(const f32x4*)&b1[dbase + 4];
        f32x4 v0 = *(const f32x4*)&b2[dbase], v1 = *(const f32x4*)&b2[dbase + 4];
        f32x4 w0 = *(const f32x4*)&W3[dbase], w1 = *(const f32x4*)&W3[dbase + 4];
        #pragma unroll
        for (int j = 0; j < 4; ++j) {
            b1v[j] = u0[j]; b1v[j + 4] = u1[j];
            b2v[j] = v0[j]; b2v[j + 4] = v1[j];
            w3v[j] = w0[j]; w3v[j + 4] = w1[j];
        }
    }
    __syncthreads();

#define EDGE_MAC(pe)                                                          \
    {                                                                         \
        float n = __uint_as_float((unsigned)(pe) << 16);                      \
        uint4 hv = *(const uint4*)&HA[((unsigned)(pe) >> 16) * HD + dbase];   \
        a[0] = fmaf(n, __uint_as_float(hv.x << 16), a[0]);                    \
        a[1] = fmaf(n, __uint_as_float(hv.x & 0xffff0000u), a[1]);            \
        a[2] = fmaf(n, __uint_as_float(hv.y << 16), a[2]);                    \
        a[3] = fmaf(n, __uint_as_float(hv.y & 0xffff0000u), a[3]);            \
        a[4] = fmaf(n, __uint_as_float(hv.z << 16), a[4]);                    \
        a[5] = fmaf(n, __uint_as_float(hv.z & 0xffff0000u), a[5]);            \
        a[6] = fmaf(n, __uint_as_float(hv.w << 16), a[6]);                    \
        a[7] = fmaf(n, __uint_as_float(hv.w & 0xffff0000u), a[7]);            \
    }

    // ---- SpMM1: h1 = relu(S @ B1 + b1) -> HB[c][d] (padded rows)
    #pragma unroll 1
    for (int set = 0; set < 4; ++set) {
        int r  = set * 128 + wave * 8 + grp;
        int e0 = sptr[r], e1 = sptr[r + 1];
        int c  = scm[r];
        float a[8];
        #pragma unroll
        for (int j = 0; j < 8; ++j) a[j] = 0.0f;
        int e = e0;
        for (; e + 2 <= e1; e += 2) {
            int pe0 = eps[e], pe1 = eps[e + 1];
            EDGE_MAC(pe0);
            EDGE_MAC(pe1);
        }
        if (e < e1) { int pe0 = eps[e]; EDGE_MAC(pe0); }
        short8 o;
        #pragma unroll
        for (int j = 0; j < 8; ++j) o[j] = f2bf(fmaxf(a[j] + b1v[j], 0.0f));
        *(short8*)&HB[c * HBS + dbase] = o;
    }
    __syncthreads();

    // ---- MFMA: g = h1 @ W2 -> HA[node][dout]  (wave = 32-node strip)
    {
        short8 bfr[2][4];
        #pragma unroll
        for (int ks = 0; ks < 2; ++ks)
            #pragma unroll
            for (int nt = 0; nt < 4; ++nt)
                bfr[ks][nt] = *(const short8*)&W2T[(nt * 16 + l15) * HD + ks * 32 + q * 8];
        f32x4 acc[2][4];
        #pragma unroll
        for (int mt = 0; mt < 2; ++mt)
            #pragma unroll
            for (int nt = 0; nt < 4; ++nt) acc[mt][nt] = (f32x4){0.f, 0.f, 0.f, 0.f};
        const int mbase = wave * 32;
        #pragma unroll
        for (int mt = 0; mt < 2; ++mt)
            #pragma unroll
            for (int ks = 0; ks < 2; ++ks) {
                short8 af = *(const short8*)&HB[(mbase + mt * 16 + l15) * HBS
                                                + ks * 32 + q * 8];
                #pragma unroll
                for (int nt = 0; nt < 4; ++nt)
                    acc[mt][nt] = __builtin_amdgcn_mfma_f32_16x16x32_bf16(
                        af, bfr[ks][nt], acc[mt][nt], 0, 0, 0);
            }
        #pragma unroll
        for (int mt = 0; mt < 2; ++mt)
            #pragma unroll
            for (int nt = 0; nt < 4; ++nt)
                #pragma unroll
                for (int i = 0; i < 4; ++i)
                    HA[(mbase + mt * 16 + q * 4 + i) * HD + nt * 16 + l15] =
                        f2bf(acc[mt][nt][i]);
    }
    __syncthreads();

    // ---- SpMM2 + fused epilogue: tv[c] = sum_d relu((S@g)[c,d] + b2[d]) * W3[d]
    #pragma unroll 1
    for (int set = 0; set < 4; ++set) {
        int r  = set * 128 + wave * 8 + grp;
        int e0 = sptr[r], e1 = sptr[r + 1];
        int c  = scm[r];
        float a[8];
        #pragma unroll
        for (int j = 0; j < 8; ++j) a[j] = 0.0f;
        int e = e0;
        for (; e + 2 <= e1; e += 2) {
            int pe0 = eps[e], pe1 = eps[e + 1];
            EDGE_MAC(pe0);
            EDGE_MAC(pe1);
        }
        if (e < e1) { int pe0 = eps[e]; EDGE_MAC(pe0); }
        float v = 0.0f;
        #pragma unroll
        for (int j = 0; j < 8; ++j)
            v += fmaxf(a[j] + b2v[j], 0.0f) * w3v[j];
        v += __shfl_xor(v, 1, 64);
        v += __shfl_xor(v, 2, 64);
        v += __shfl_xor(v, 4, 64);
        if ((lane & 7) == 0) tv[c] = v;
    }
    __syncthreads();

    // ---- SpMM3: slog[c] = (S @ tv)[c] + b3   (one rank per thread)
    if (t < NUM) {
        int e0 = sptr[t], e1 = sptr[t + 1];
        float a = 0.0f;
        for (int e = e0; e < e1; ++e) {
            unsigned pe = (unsigned)eps[e];
            a = fmaf(__uint_as_float(pe << 16), tv[pe >> 16], a);
        }
        slog[scm[t]] = a + b3[0];
    }
    __syncthreads();

    // ---- softmax stats over [0, MAIN)
    if (t < 64) {
        float v = (t < MAIN) ? slog[t] : -1e30f;
        float m = v;
        m = fmaxf(m, __shfl_xor(m, 1, 64));
        m = fmaxf(m, __shfl_xor(m, 2, 64));
        m = fmaxf(m, __shfl_xor(m, 4, 64));
        m = fmaxf(m, __shfl_xor(m, 8, 64));
        float ev = (t < MAIN) ? __expf(v - m) : 0.0f;
        ev += __shfl_xor(ev, 1, 64);
        ev += __shfl_xor(ev, 2, 64);
        ev += __shfl_xor(ev, 4, 64);
        ev += __shfl_xor(ev, 8, 64);
        if (t == 0) { sred[0] = m; sred[1] = ev; }
    }
    __syncthreads();

    if (t < NUM) {
        float l = slog[t];
        float o = (t < MAIN) ? __expf(l - sred[0]) / sred[1]
                             : 1.0f / (1.0f + __expf(-l));
        out[b * NUM + t] = o;
    }
#undef EDGE_MAC
}

// ---------------------------------------------------------------------------
extern "C" void kernel_launch(void* const* d_in, const int* in_sizes, int n_in,
                              void* d_out, int out_size, void* d_ws, size_t ws_size,
                              hipStream_t stream) {
    const float* x    = (const float*)d_in[0];
    const float* emb  = (const float*)d_in[1];
    const float* W1   = (const float*)d_in[2];
    const float* b1   = (const float*)d_in[3];
    const float* W2   = (const float*)d_in[4];
    const float* b2   = (const float*)d_in[5];
    const float* W3   = (const float*)d_in[6];
    const float* b3   = (const float*)d_in[7];
    const int*   erow = (const int*)d_in[8];
    const int*   ecol = (const int*)d_in[9];

    char* ws = (char*)d_ws;
    int*   rsptr  = (int*)ws;                // 513 ints  [0, 2052)
    int*   colmap = (int*)(ws + 2176);       // 512 ints  [2176, 4224)
    int*   epk    = (int*)(ws + 4224);       // 4096 ints [4224, 20608)
    short* E1     = (short*)(ws + 20608);    // 32768 sh  [20608, 86144)
    short* W2T    = (short*)(ws + 86144);    // 4096 sh   [86144, 94336)

    prep_all<<<73, 512, 0, stream>>>(erow, ecol, emb, W1, W2,
                                     rsptr, colmap, epk, E1, W2T);
    gcn_all<<<NB, 1024, 0, stream>>>(x, E1, W2T, b1, b2, W3, b3,
                                     rsptr, colmap, epk, (float*)d_out);
}